// Round 8
// baseline (1031.664 us; speedup 1.0000x reference)
//
#include <hip/hip_runtime.h>

// ALiBi bias: out[h,i,j] = (j > i) ? -slopes[h]*(j-i) : 0
// H=16, S=4096, float32 [16,4096,4096] = 1.074 GB. Pure write-BW-bound.
//
// R8: single variable vs R6/R7 — 512 blocks (2 blocks/CU, 8 waves/CU) instead
// of 256. Theory: write-path Little's law; at 4 waves/CU our ~25% VALU duty
// leaves store-issue gaps that drain the per-CU write queue (probe: 5.6 TB/s
// vs fill 6.5 at identical shape). Doubling waves/CU doubles issue density and
// in-flight store capacity; marching window 1->2 MB, still dense.
// Probe kept code-identical to R7's (only grid changed) for a clean A/B.

#define ALIBI_S 4096
#define ALIBI_H 16
#define BLOCK   256
#define GRID    512          // 2 blocks per CU
#define N_F4    (1u << 26)   // H*S*S/4 float4 elements
#define STRIDE  (GRID * BLOCK)          // 131072 float4s = 2 MB per sweep
#define ITERS   (N_F4 / STRIDE)         // 512

typedef float f32x4 __attribute__((ext_vector_type(4)));

__global__ __launch_bounds__(BLOCK) void alibi_bias_kernel(
    const float* __restrict__ slopes,
    f32x4* __restrict__ out)
{
    __shared__ float ns_s[ALIBI_H];
    if (threadIdx.x < ALIBI_H) ns_s[threadIdx.x] = -slopes[threadIdx.x];
    __syncthreads();

    unsigned int f = blockIdx.x * BLOCK + threadIdx.x;  // float4 index

#pragma unroll 4
    for (int it = 0; it < ITERS; ++it, f += STRIDE) {
        const unsigned int e = f << 2;           // element index (max 2^28)
        const int h = (int)(e >> 24);            // plane (wave-uniform)
        const float ns = ns_s[h];
        const int i = (int)((e >> 12) & 4095u);  // row
        const int j = (int)(e & 4095u);          // first of 4 consecutive cols

        f32x4 v;
        v.x = (j + 0 > i) ? ns * (float)(j + 0 - i) : 0.0f;
        v.y = (j + 1 > i) ? ns * (float)(j + 1 - i) : 0.0f;
        v.z = (j + 2 > i) ? ns * (float)(j + 2 - i) : 0.0f;
        v.w = (j + 3 > i) ? ns * (float)(j + 3 - i) : 0.0f;

        out[f] = v;
    }
}

// Diagnostic: code-identical to R7's probe; only the launch grid changes.
__global__ __launch_bounds__(BLOCK) void ws_fillmimic_probe(
    const float* __restrict__ slopes,
    f32x4* __restrict__ ws,
    size_t n4)
{
    __shared__ float ns_s[ALIBI_H];
    if (threadIdx.x < ALIBI_H) ns_s[threadIdx.x] = -slopes[threadIdx.x];
    __syncthreads();

    size_t f = (size_t)blockIdx.x * BLOCK + threadIdx.x;
    const size_t stride = (size_t)gridDim.x * BLOCK;

    for (; f < n4; f += stride) {
        const unsigned int e = (unsigned int)(f << 2);
        const int h = (int)((e >> 24) & 15u);
        const float ns = ns_s[h];
        const int i = (int)((e >> 12) & 4095u);
        const int j = (int)(e & 4095u);

        f32x4 v;
        v.x = (j + 0 > i) ? ns * (float)(j + 0 - i) : 0.0f;
        v.y = (j + 1 > i) ? ns * (float)(j + 1 - i) : 0.0f;
        v.z = (j + 2 > i) ? ns * (float)(j + 2 - i) : 0.0f;
        v.w = (j + 3 > i) ? ns * (float)(j + 3 - i) : 0.0f;

        ws[f] = v;
    }
}

extern "C" void kernel_launch(void* const* d_in, const int* in_sizes, int n_in,
                              void* d_out, int out_size, void* d_ws, size_t ws_size,
                              hipStream_t stream) {
    const float* slopes = (const float*)d_in[0];
    f32x4* out = (f32x4*)d_out;

    // Real output kernel (R6 structure, grid 512).
    alibi_bias_kernel<<<GRID, BLOCK, 0, stream>>>(slopes, out);

    // Diagnostic probe over the whole workspace (grid 512).
    const size_t n4 = ws_size / 16;
    if (n4 > 0) {
        ws_fillmimic_probe<<<GRID, BLOCK, 0, stream>>>(slopes, (f32x4*)d_ws, n4);
    }
}

// Round 9
// 201.553 us; speedup vs baseline: 5.1186x; 5.1186x over previous
//
#include <hip/hip_runtime.h>

// ALiBi bias: out[h,i,j] = (j > i) ? -slopes[h]*(j-i) : 0
// H=16, S=4096, float32 [16,4096,4096] = 1.074 GB. Pure write-BW-bound.
//
// R9: lean-loop triangle split. Evidence so far: dense marching window +
// 1 block/CU (R6) is best; more waves hurt (R8); the remaining gap to
// rocclr fill (6.5 TB/s, VALUBusy 5%) correlates with VALU work between
// stores. Each wave-iteration = one 256-element chunk inside one row, so the
// chunk class is wave-uniform (readfirstlane -> scalar branch):
//   zero chunk (~47%): store pre-zeroed reg (no compute, no LDS)
//   ramp chunk (~47%): v0 = ns*d0, then +ns increments (5 VALU)
//   mixed (~6%, contains diagonal): per-component select
// Grid 256 x 256 (1 block/CU), unroll 4, dense 1 MB window.

#define ALIBI_S 4096
#define ALIBI_H 16
#define BLOCK   256
#define GRID    256
#define N_F4    (1u << 26)              // H*S*S/4 float4 elements
#define STRIDE  (GRID * BLOCK)          // 65536 float4s = 1 MB window
#define ITERS   (N_F4 / STRIDE)         // 1024

typedef float f32x4 __attribute__((ext_vector_type(4)));

__global__ __launch_bounds__(BLOCK) void alibi_bias_kernel(
    const float* __restrict__ slopes,
    f32x4* __restrict__ out)
{
    __shared__ float ns_s[ALIBI_H];
    if (threadIdx.x < ALIBI_H) ns_s[threadIdx.x] = -slopes[threadIdx.x];
    __syncthreads();

    unsigned int f = blockIdx.x * BLOCK + threadIdx.x;  // per-lane float4 index
    const f32x4 zero4 = {0.0f, 0.0f, 0.0f, 0.0f};

#pragma unroll 4
    for (int it = 0; it < ITERS; ++it, f += STRIDE) {
        // Wave-uniform chunk descriptor (chunk = 64 lanes x 4 floats = 256
        // elements, always inside one row since 256 | 4096).
        const unsigned int fw = __builtin_amdgcn_readfirstlane(f);
        const unsigned int ew = fw << 2;
        const int s_h  = (int)(ew >> 24);
        const int s_i  = (int)((ew >> 12) & 4095u);
        const int s_j0 = (int)(ew & 4095u);

        if (s_j0 + 255 <= s_i) {
            // Entire chunk is past/current (j <= i): zeros. No compute.
            out[f] = zero4;
        } else {
            const float ns  = ns_s[s_h];          // LDS broadcast (uniform addr)
            const int   d0  = (int)((f << 2) & 4095u) - s_i;  // j - i, comp 0
            if (s_j0 > s_i) {
                // Entire chunk strictly future: pure ramp.
                const float v0 = ns * (float)d0;
                const float ns2 = ns + ns;
                f32x4 v;
                v.x = v0;
                v.y = v0 + ns;
                v.z = v0 + ns2;
                v.w = v0 + ns2 + ns;
                out[f] = v;
            } else {
                // Mixed chunk (contains the diagonal): per-component select.
                f32x4 v;
                v.x = (d0 > 0)     ? ns * (float)d0       : 0.0f;
                v.y = (d0 + 1 > 0) ? ns * (float)(d0 + 1) : 0.0f;
                v.z = (d0 + 2 > 0) ? ns * (float)(d0 + 2) : 0.0f;
                v.w = (d0 + 3 > 0) ? ns * (float)(d0 + 3) : 0.0f;
                out[f] = v;
            }
        }
    }
}

extern "C" void kernel_launch(void* const* d_in, const int* in_sizes, int n_in,
                              void* d_out, int out_size, void* d_ws, size_t ws_size,
                              hipStream_t stream) {
    const float* slopes = (const float*)d_in[0];
    f32x4* out = (f32x4*)d_out;
    alibi_bias_kernel<<<GRID, BLOCK, 0, stream>>>(slopes, out);
}

// Round 10
// 186.334 us; speedup vs baseline: 5.5366x; 1.0817x over previous
//
#include <hip/hip_runtime.h>

// ALiBi bias: out[h,i,j] = (j > i) ? -slopes[h]*(j-i) : 0
// H=16, S=4096, float32 [16,4096,4096] = 1.074 GB. Pure write-BW-bound.
//
// R10: branch-free lean loop exploiting the marching structure.
// With GRID=256, BLOCK=256, stride = 65536 float4s = exactly 64 rows:
//   - j (column) is CONSTANT per thread for the whole kernel
//   - i advances by exactly 64 per iteration (64 iters per plane)
//   - h changes only at plane boundaries (outer loop)
// So per plane the 4 lane-values form arithmetic sequences:
//   r_k = ns*(j+k-i),  r += (-64*ns) per iteration,
// and the causal mask is a single min:  out = min(r, 0)
//   (ns < 0  =>  ns*d < 0 iff d > 0; for d <= 0, r >= 0 -> clamped to 0;
//    -0 vs +0 is a zero absmax difference).
// Inner iteration: 4 v_add + 4 v_min + addr add + store. No LDS, no cvt,
// no branches. Incremental FP error <= ~64 * ulp(2896) ~ 0.015 << 57.92.

#define ALIBI_S 4096
#define ALIBI_H 16
#define BLOCK   256
#define GRID    256
#define STRIDE  (GRID * BLOCK)   // 65536 float4s = 1 MB window = 64 rows

typedef float f32x4 __attribute__((ext_vector_type(4)));

__global__ __launch_bounds__(BLOCK) void alibi_bias_kernel(
    const float* __restrict__ slopes,
    f32x4* __restrict__ out)
{
    const unsigned int tidf = blockIdx.x * BLOCK + threadIdx.x;  // float4 idx in sweep
    const unsigned int e0 = tidf << 2;
    const int j  = (int)(e0 & 4095u);   // constant column (first of 4)
    const int i0 = (int)(e0 >> 12);     // starting row, 0..63
    const int d0 = j - i0;

    for (int h = 0; h < ALIBI_H; ++h) {
        const float ns   = -slopes[h];        // wave-uniform scalar load
        const float step = -64.0f * ns;       // exact (64 = 2^6)

        f32x4 r;
        r.x = ns * (float)(d0 + 0);
        r.y = ns * (float)(d0 + 1);
        r.z = ns * (float)(d0 + 2);
        r.w = ns * (float)(d0 + 3);

        unsigned int fb = ((unsigned int)h << 22) + tidf;

#pragma unroll 8
        for (int it = 0; it < 64; ++it) {
            f32x4 v;
            v.x = fminf(r.x, 0.0f);
            v.y = fminf(r.y, 0.0f);
            v.z = fminf(r.z, 0.0f);
            v.w = fminf(r.w, 0.0f);
            out[fb] = v;
            r.x += step; r.y += step; r.z += step; r.w += step;
            fb += STRIDE;
        }
    }
}

extern "C" void kernel_launch(void* const* d_in, const int* in_sizes, int n_in,
                              void* d_out, int out_size, void* d_ws, size_t ws_size,
                              hipStream_t stream) {
    const float* slopes = (const float*)d_in[0];
    f32x4* out = (f32x4*)d_out;
    alibi_bias_kernel<<<GRID, BLOCK, 0, stream>>>(slopes, out);
}